// Round 3
// baseline (2570.680 us; speedup 1.0000x reference)
//
#include <hip/hip_runtime.h>

#define HDIM 32
#define IN_DIM 128
#define NEG_SLOPE 0.2f
#define NPB 128            // nodes per bucket (power of 2)
#define NPB_SHIFT 7
#define ACC_STRIDE 33      // 33 coprime with 32 banks -> conflict-free ds_add

__device__ __forceinline__ float leaky(float e) {
    return (e >= 0.f) ? e : NEG_SLOPE * e;
}

// ---------------- GEMM kernels ----------------

__global__ __launch_bounds__(256) void gemm128(
    const float* __restrict__ x, const float* __restrict__ W,
    const float* __restrict__ a_s, const float* __restrict__ a_d,
    float* __restrict__ h, float* __restrict__ es, float* __restrict__ ed, int N)
{
    __shared__ float Ws[IN_DIM * HDIM];
    __shared__ float xs[8][IN_DIM];
    const int tid = threadIdx.x;
    for (int i = tid; i < IN_DIM * HDIM; i += 256) Ws[i] = W[i];
    const int col = tid & 31;
    const int rl  = tid >> 5;
    const float as_c = a_s[col], ad_c = a_d[col];
    for (int tile = blockIdx.x; tile * 8 < N; tile += gridDim.x) {
        const int row0 = tile * 8;
        __syncthreads();
        for (int i = tid; i < 8 * IN_DIM; i += 256) {
            int r = i >> 7, c = i & 127;
            int gr = row0 + r;
            xs[r][c] = (gr < N) ? x[(size_t)gr * IN_DIM + c] : 0.f;
        }
        __syncthreads();
        const int row = row0 + rl;
        float acc = 0.f;
        #pragma unroll 8
        for (int k = 0; k < IN_DIM; k++) acc += xs[rl][k] * Ws[k * HDIM + col];
        float ps = acc * as_c, pd = acc * ad_c;
        #pragma unroll
        for (int m = 16; m >= 1; m >>= 1) { ps += __shfl_xor(ps, m); pd += __shfl_xor(pd, m); }
        if (row < N) {
            h[(size_t)row * HDIM + col] = acc;
            if (col == 0) { es[row] = ps; ed[row] = pd; }
        }
    }
}

__global__ __launch_bounds__(256) void gemm32(
    const float* __restrict__ x, const float* __restrict__ W,
    const float* __restrict__ a_s, const float* __restrict__ a_d,
    float* __restrict__ h, float* __restrict__ es, float* __restrict__ ed, int N)
{
    __shared__ float Ws[HDIM * HDIM];
    __shared__ float xs[8][HDIM];
    const int tid = threadIdx.x;
    for (int i = tid; i < HDIM * HDIM; i += 256) Ws[i] = W[i];
    const int col = tid & 31;
    const int rl  = tid >> 5;
    const float as_c = a_s[col], ad_c = a_d[col];
    for (int tile = blockIdx.x; tile * 8 < N; tile += gridDim.x) {
        const int row0 = tile * 8;
        __syncthreads();
        {
            int r = tid >> 5, c = tid & 31;
            int gr = row0 + r;
            xs[r][c] = (gr < N) ? x[(size_t)gr * HDIM + c] : 0.f;
        }
        __syncthreads();
        const int row = row0 + rl;
        float acc = 0.f;
        #pragma unroll
        for (int k = 0; k < HDIM; k++) acc += xs[rl][k] * Ws[k * HDIM + col];
        float ps = acc * as_c, pd = acc * ad_c;
        #pragma unroll
        for (int m = 16; m >= 1; m >>= 1) { ps += __shfl_xor(ps, m); pd += __shfl_xor(pd, m); }
        if (row < N) {
            h[(size_t)row * HDIM + col] = acc;
            if (col == 0) { es[row] = ps; ed[row] = pd; }
        }
    }
}

// ---------------- Coarse bucket build (once per call) ----------------

__global__ __launch_bounds__(256) void bucket_hist(
    const int* __restrict__ dsts, int E, int* __restrict__ bcnt)
{
    int e = blockIdx.x * blockDim.x + threadIdx.x;
    if (e < E) atomicAdd(&bcnt[dsts[e] >> NPB_SHIFT], 1);
}

// single-block exclusive scan over B (<=1024) bucket counts
__global__ __launch_bounds__(1024) void bucket_scan(
    const int* __restrict__ bcnt, int B, int E,
    int* __restrict__ bstart, int* __restrict__ cursor)
{
    __shared__ int sdata[1024];
    int t = threadIdx.x;
    int v = (t < B) ? bcnt[t] : 0;
    sdata[t] = v;
    __syncthreads();
    for (int off = 1; off < 1024; off <<= 1) {
        int add = (t >= off) ? sdata[t - off] : 0;
        __syncthreads();
        sdata[t] += add;
        __syncthreads();
    }
    if (t < B) {
        int excl = sdata[t] - v;
        bstart[t] = excl;
        cursor[t] = excl;
        if (t == B - 1) bstart[B] = E;
    }
}

// scatter packed records (src<<7)|(dst&127) into bucket-grouped array
__global__ __launch_bounds__(256) void pair_scatter(
    const int* __restrict__ srcs, const int* __restrict__ dsts, int E,
    int* __restrict__ cursor, int* __restrict__ pairs)
{
    int e = blockIdx.x * blockDim.x + threadIdx.x;
    if (e >= E) return;
    int s = srcs[e], d = dsts[e];
    int idx = atomicAdd(&cursor[d >> NPB_SHIFT], 1);
    pairs[idx] = (s << NPB_SHIFT) | (d & (NPB - 1));
}

// ---------------- Aggregation: one block per bucket, LDS accumulators ------

__global__ __launch_bounds__(256) void bucket_agg(
    const float* __restrict__ h, const float* __restrict__ es, const float* __restrict__ ed,
    const int* __restrict__ pairs, const int* __restrict__ bstart,
    const float* __restrict__ b, float* __restrict__ out, int N)
{
    __shared__ float acc[NPB * ACC_STRIDE];   // 16.9 KB: [node][0..31]=feat, [32]=denom
    __shared__ float eds[NPB];
    const int tid  = threadIdx.x;
    const int lane = tid & 31;
    const int hw   = tid >> 5;                // 8 half-waves
    const int node0 = blockIdx.x * NPB;

    for (int i = tid; i < NPB * ACC_STRIDE; i += 256) acc[i] = 0.f;
    for (int i = tid; i < NPB; i += 256) {
        int n = node0 + i;
        eds[i] = (n < N) ? ed[n] : 0.f;
    }
    __syncthreads();

    const int e0 = bstart[blockIdx.x];
    const int e1 = bstart[blockIdx.x + 1];
    for (int e = e0 + hw; e < e1; e += 8) {
        int p  = pairs[e];
        int s  = p >> NPB_SHIFT;
        int ld = p & (NPB - 1);
        float w = __expf(leaky(es[s] + eds[ld]));
        atomicAdd(&acc[ld * ACC_STRIDE + lane], w * h[(size_t)s * HDIM + lane]);
        if (lane == 0) atomicAdd(&acc[ld * ACC_STRIDE + 32], w);
    }
    __syncthreads();

    // epilogue: self-loop + divide + bias, coalesced writes
    const float bf = b[lane];
    for (int i = tid; i < NPB * HDIM; i += 256) {
        int ln = i >> 5;
        int n  = node0 + ln;
        if (n < N) {
            float w   = __expf(leaky(es[n] + eds[ln]));
            float num = acc[ln * ACC_STRIDE + lane] + w * h[(size_t)n * HDIM + lane];
            float den = acc[ln * ACC_STRIDE + 32] + w;
            out[(size_t)n * HDIM + lane] = num / den + bf;
        }
    }
}

// ---------------- Pool ----------------

__global__ __launch_bounds__(256) void pool_kernel(
    const float* __restrict__ x, const int* __restrict__ batch,
    float* __restrict__ psum, float* __restrict__ pcnt, int N)
{
    int t = blockIdx.x * blockDim.x + threadIdx.x;
    int lane = t & 31, i = t >> 5;
    if (i >= N) return;
    int g = batch[i];
    atomicAdd(&psum[(size_t)g * HDIM + lane], x[(size_t)i * HDIM + lane]);
    if (lane == 0) atomicAdd(&pcnt[g], 1.f);
}

__global__ __launch_bounds__(256) void pool_div(
    const float* __restrict__ psum, const float* __restrict__ pcnt,
    float* __restrict__ out, int G)
{
    int t = blockIdx.x * blockDim.x + threadIdx.x;
    if (t >= G * HDIM) return;
    int g = t >> 5;
    out[t] = psum[t] / fmaxf(pcnt[g], 1.f);
}

// ---------------- Launch ----------------

extern "C" void kernel_launch(void* const* d_in, const int* in_sizes, int n_in,
                              void* d_out, int out_size, void* d_ws, size_t ws_size,
                              hipStream_t stream) {
    const float* x          = (const float*)d_in[0];
    const int*   edge_index = (const int*)d_in[1];
    const int*   batch      = (const int*)d_in[2];

    const int N = in_sizes[2];          // 100000
    const int E = in_sizes[1] / 2;      // 1600000
    const int G = out_size / HDIM;      // 2048
    const int B = (N + NPB - 1) / NPB;  // 782 buckets (<=1024 required by scan)

    const int* srcs = edge_index;
    const int* dsts = edge_index + E;

    // workspace layout
    char* p = (char*)d_ws;
    float* h      = (float*)p; p += (size_t)N * HDIM * sizeof(float);
    float* xbuf   = (float*)p; p += (size_t)N * HDIM * sizeof(float);
    float* es     = (float*)p; p += (size_t)N * sizeof(float);
    float* ed     = (float*)p; p += (size_t)N * sizeof(float);
    int*   pairs  = (int*)p;   p += (size_t)E * sizeof(int);
    int*   bcnt   = (int*)p;   p += (size_t)B * sizeof(int);
    int*   bstart = (int*)p;   p += (size_t)(B + 1) * sizeof(int);
    int*   cursor = (int*)p;   p += (size_t)B * sizeof(int);
    float* psum   = (float*)p; p += (size_t)G * HDIM * sizeof(float);
    float* pcnt   = (float*)p; p += (size_t)G * sizeof(float);

    // ---- bucket build (once; same edge set for all 4 layers) ----
    hipMemsetAsync(bcnt, 0, (size_t)B * sizeof(int), stream);
    bucket_hist<<<(E + 255) / 256, 256, 0, stream>>>(dsts, E, bcnt);
    bucket_scan<<<1, 1024, 0, stream>>>(bcnt, B, E, bstart, cursor);
    pair_scatter<<<(E + 255) / 256, 256, 0, stream>>>(srcs, dsts, E, cursor, pairs);

    // ---- 4 GAT layers ----
    const float* xin = x;
    for (int l = 0; l < 4; l++) {
        const float* W   = (const float*)d_in[3 + 4 * l];
        const float* a_s = (const float*)d_in[4 + 4 * l];
        const float* a_d = (const float*)d_in[5 + 4 * l];
        const float* bb  = (const float*)d_in[6 + 4 * l];

        if (l == 0) gemm128<<<2048, 256, 0, stream>>>(xin, W, a_s, a_d, h, es, ed, N);
        else        gemm32 <<<2048, 256, 0, stream>>>(xin, W, a_s, a_d, h, es, ed, N);

        bucket_agg<<<B, 256, 0, stream>>>(h, es, ed, pairs, bstart, bb, xbuf, N);
        xin = xbuf;
    }

    // ---- global mean pool ----
    hipMemsetAsync(psum, 0, (size_t)(G * HDIM + G) * sizeof(float), stream);
    pool_kernel<<<(N * 32 + 255) / 256, 256, 0, stream>>>(xbuf, batch, psum, pcnt, N);
    pool_div<<<(G * HDIM + 255) / 256, 256, 0, stream>>>(psum, pcnt, (float*)d_out, G);
}

// Round 4
// 494.460 us; speedup vs baseline: 5.1990x; 5.1990x over previous
//
#include <hip/hip_runtime.h>

#define HDIM 32
#define IN_DIM 128
#define NEG_SLOPE 0.2f
#define NPB 128            // nodes per coarse bucket (power of 2)
#define NPB_SHIFT 7
#define MAXB 1024          // max buckets (B = ceil(N/128) = 782)
#define CHUNK 8192         // edges per chunk block
#define CAP 4096           // max records per bucket for LDS sort fast path

__device__ __forceinline__ float leaky(float e) {
    return (e >= 0.f) ? e : NEG_SLOPE * e;
}

// ---------------- GEMM kernels ----------------

__global__ __launch_bounds__(256) void gemm128(
    const float* __restrict__ x, const float* __restrict__ W,
    const float* __restrict__ a_s, const float* __restrict__ a_d,
    float* __restrict__ h, float* __restrict__ es, float* __restrict__ ed, int N)
{
    __shared__ float Ws[IN_DIM * HDIM];
    __shared__ float xs[8][IN_DIM];
    const int tid = threadIdx.x;
    for (int i = tid; i < IN_DIM * HDIM; i += 256) Ws[i] = W[i];
    const int col = tid & 31;
    const int rl  = tid >> 5;
    const float as_c = a_s[col], ad_c = a_d[col];
    for (int tile = blockIdx.x; tile * 8 < N; tile += gridDim.x) {
        const int row0 = tile * 8;
        __syncthreads();
        for (int i = tid; i < 8 * IN_DIM; i += 256) {
            int r = i >> 7, c = i & 127;
            int gr = row0 + r;
            xs[r][c] = (gr < N) ? x[(size_t)gr * IN_DIM + c] : 0.f;
        }
        __syncthreads();
        const int row = row0 + rl;
        float acc = 0.f;
        #pragma unroll 8
        for (int k = 0; k < IN_DIM; k++) acc += xs[rl][k] * Ws[k * HDIM + col];
        float ps = acc * as_c, pd = acc * ad_c;
        #pragma unroll
        for (int m = 16; m >= 1; m >>= 1) { ps += __shfl_xor(ps, m); pd += __shfl_xor(pd, m); }
        if (row < N) {
            h[(size_t)row * HDIM + col] = acc;
            if (col == 0) { es[row] = ps; ed[row] = pd; }
        }
    }
}

__global__ __launch_bounds__(256) void gemm32(
    const float* __restrict__ x, const float* __restrict__ W,
    const float* __restrict__ a_s, const float* __restrict__ a_d,
    float* __restrict__ h, float* __restrict__ es, float* __restrict__ ed, int N)
{
    __shared__ float Ws[HDIM * HDIM];
    __shared__ float xs[8][HDIM];
    const int tid = threadIdx.x;
    for (int i = tid; i < HDIM * HDIM; i += 256) Ws[i] = W[i];
    const int col = tid & 31;
    const int rl  = tid >> 5;
    const float as_c = a_s[col], ad_c = a_d[col];
    for (int tile = blockIdx.x; tile * 8 < N; tile += gridDim.x) {
        const int row0 = tile * 8;
        __syncthreads();
        {
            int r = tid >> 5, c = tid & 31;
            int gr = row0 + r;
            xs[r][c] = (gr < N) ? x[(size_t)gr * HDIM + c] : 0.f;
        }
        __syncthreads();
        const int row = row0 + rl;
        float acc = 0.f;
        #pragma unroll
        for (int k = 0; k < HDIM; k++) acc += xs[rl][k] * Ws[k * HDIM + col];
        float ps = acc * as_c, pd = acc * ad_c;
        #pragma unroll
        for (int m = 16; m >= 1; m >>= 1) { ps += __shfl_xor(ps, m); pd += __shfl_xor(pd, m); }
        if (row < N) {
            h[(size_t)row * HDIM + col] = acc;
            if (col == 0) { es[row] = ps; ed[row] = pd; }
        }
    }
}

// ---------------- Two-level CSR build (once per call) ----------------

// Pass 1: per-chunk LDS histogram over coarse buckets
__global__ __launch_bounds__(256) void chunk_hist(
    const int* __restrict__ dsts, int E, int B, int* __restrict__ cnt2D)
{
    __shared__ int hist[MAXB];
    const int blk = blockIdx.x;
    for (int i = threadIdx.x; i < B; i += 256) hist[i] = 0;
    __syncthreads();
    const int e0 = blk * CHUNK;
    for (int i = threadIdx.x; i < CHUNK; i += 256) {
        int e = e0 + i;
        if (e < E) atomicAdd(&hist[dsts[e] >> NPB_SHIFT], 1);
    }
    __syncthreads();
    for (int i = threadIdx.x; i < B; i += 256) cnt2D[(size_t)blk * B + i] = hist[i];
}

// Pass 2a: per-bucket exclusive scan over chunks -> off2D, bucket totals
__global__ __launch_bounds__(256) void chunk_scan(
    const int* __restrict__ cnt2D, int NBLK, int B,
    int* __restrict__ off2D, int* __restrict__ bcnt)
{
    __shared__ int s[256];
    const int b = blockIdx.x, t = threadIdx.x;
    int v = (t < NBLK) ? cnt2D[(size_t)t * B + b] : 0;
    s[t] = v;
    __syncthreads();
    for (int off = 1; off < 256; off <<= 1) {
        int add = (t >= off) ? s[t - off] : 0;
        __syncthreads();
        s[t] += add;
        __syncthreads();
    }
    if (t < NBLK) off2D[(size_t)t * B + b] = s[t] - v;
    if (t == 255) bcnt[b] = s[255];
}

// Pass 2b: exclusive scan over buckets -> bstart; also rowptr[N]=E
__global__ __launch_bounds__(1024) void bucket_scan(
    const int* __restrict__ bcnt, int B, int E,
    int* __restrict__ bstart, int* __restrict__ rowptr, int N)
{
    __shared__ int s[1024];
    const int t = threadIdx.x;
    int v = (t < B) ? bcnt[t] : 0;
    s[t] = v;
    __syncthreads();
    for (int off = 1; off < 1024; off <<= 1) {
        int add = (t >= off) ? s[t - off] : 0;
        __syncthreads();
        s[t] += add;
        __syncthreads();
    }
    if (t < B) bstart[t] = s[t] - v;
    if (t == 0) { bstart[B] = E; rowptr[N] = E; }
}

// Pass 3: scatter packed records into bucket-grouped array, LDS cursors
__global__ __launch_bounds__(256) void pair_scatter2(
    const int* __restrict__ srcs, const int* __restrict__ dsts, int E, int B,
    const int* __restrict__ off2D, const int* __restrict__ bstart,
    int* __restrict__ pairs)
{
    __shared__ int cur[MAXB];
    const int blk = blockIdx.x;
    for (int i = threadIdx.x; i < B; i += 256)
        cur[i] = bstart[i] + off2D[(size_t)blk * B + i];
    __syncthreads();
    const int e0 = blk * CHUNK;
    for (int i = threadIdx.x; i < CHUNK; i += 256) {
        int e = e0 + i;
        if (e < E) {
            int s = srcs[e], d = dsts[e];
            int pos = atomicAdd(&cur[d >> NPB_SHIFT], 1);
            pairs[pos] = (s << NPB_SHIFT) | (d & (NPB - 1));
        }
    }
}

// Pass 4: per-bucket LDS sort -> exact per-node CSR (rowptr + csrsrc), coalesced
__global__ __launch_bounds__(256) void bucket_sort(
    const int* __restrict__ pairs, const int* __restrict__ bstart,
    int* __restrict__ rowptr, int* __restrict__ csrsrc, int N)
{
    __shared__ int ldeg[NPB];
    __shared__ int lex[NPB];
    __shared__ int recs[CAP];
    __shared__ int sorted[CAP];
    const int b = blockIdx.x, t = threadIdx.x;
    const int p0 = bstart[b], p1 = bstart[b + 1];
    const int cnt = p1 - p0;
    if (t < NPB) ldeg[t] = 0;
    __syncthreads();
    for (int i = t; i < cnt; i += 256) {
        int r = pairs[p0 + i];
        atomicAdd(&ldeg[r & (NPB - 1)], 1);
        if (i < CAP) recs[i] = r;
    }
    __syncthreads();
    if (t < NPB) lex[t] = ldeg[t];
    __syncthreads();
    for (int off = 1; off < NPB; off <<= 1) {
        int add = (t >= off && t < NPB) ? lex[t - off] : 0;
        __syncthreads();
        if (t < NPB) lex[t] += add;
        __syncthreads();
    }
    const int node0 = b * NPB;
    if (t < NPB) {
        int excl = lex[t] - ldeg[t];
        if (node0 + t < N) rowptr[node0 + t] = p0 + excl;
        ldeg[t] = excl;   // reuse as local cursor
    }
    __syncthreads();
    if (cnt <= CAP) {
        for (int i = t; i < cnt; i += 256) {
            int r = recs[i];
            int pos = atomicAdd(&ldeg[r & (NPB - 1)], 1);
            sorted[pos] = r >> NPB_SHIFT;
        }
        __syncthreads();
        for (int i = t; i < cnt; i += 256) csrsrc[p0 + i] = sorted[i];
    } else {
        // fallback (pathological bucket): scattered global writes, still correct
        for (int i = t; i < cnt; i += 256) {
            int r = pairs[p0 + i];
            int pos = atomicAdd(&ldeg[r & (NPB - 1)], 1);
            csrsrc[p0 + pos] = r >> NPB_SHIFT;
        }
    }
}

// ---------------- Aggregation: 8 lanes per node, float4 register acc -------

__global__ __launch_bounds__(256) void agg2(
    const float* __restrict__ h, const float* __restrict__ es, const float* __restrict__ ed,
    const int* __restrict__ rowptr, const int* __restrict__ csrsrc,
    const float* __restrict__ b, float* __restrict__ out, int N)
{
    const int gid  = blockIdx.x * 256 + threadIdx.x;
    const int node = gid >> 3;
    const int l    = threadIdx.x & 7;
    if (node >= N) return;

    const int e0 = rowptr[node];
    const int e1 = rowptr[node + 1];
    const float edi = ed[node];
    const float4* __restrict__ h4 = (const float4*)h;

    float ax = 0.f, ay = 0.f, az = 0.f, aw = 0.f, den = 0.f;
    #pragma unroll 2
    for (int e = e0; e < e1; e++) {
        int s = csrsrc[e];
        float w = __expf(leaky(es[s] + edi));
        float4 hv = h4[(size_t)s * 8 + l];
        ax += w * hv.x; ay += w * hv.y; az += w * hv.z; aw += w * hv.w;
        den += w;
    }
    {   // self-loop
        float w = __expf(leaky(es[node] + edi));
        float4 hv = h4[(size_t)node * 8 + l];
        ax += w * hv.x; ay += w * hv.y; az += w * hv.z; aw += w * hv.w;
        den += w;
    }
    float4 bv = ((const float4*)b)[l];
    float inv = 1.f / den;
    float4 o;
    o.x = ax * inv + bv.x; o.y = ay * inv + bv.y;
    o.z = az * inv + bv.z; o.w = aw * inv + bv.w;
    ((float4*)out)[(size_t)node * 8 + l] = o;
}

// ---------------- Pool ----------------

__global__ __launch_bounds__(256) void pool_kernel(
    const float* __restrict__ x, const int* __restrict__ batch,
    float* __restrict__ psum, float* __restrict__ pcnt, int N)
{
    int t = blockIdx.x * blockDim.x + threadIdx.x;
    int lane = t & 31, i = t >> 5;
    if (i >= N) return;
    int g = batch[i];
    atomicAdd(&psum[(size_t)g * HDIM + lane], x[(size_t)i * HDIM + lane]);
    if (lane == 0) atomicAdd(&pcnt[g], 1.f);
}

__global__ __launch_bounds__(256) void pool_div(
    const float* __restrict__ psum, const float* __restrict__ pcnt,
    float* __restrict__ out, int G)
{
    int t = blockIdx.x * blockDim.x + threadIdx.x;
    if (t >= G * HDIM) return;
    int g = t >> 5;
    out[t] = psum[t] / fmaxf(pcnt[g], 1.f);
}

// ---------------- Launch ----------------

extern "C" void kernel_launch(void* const* d_in, const int* in_sizes, int n_in,
                              void* d_out, int out_size, void* d_ws, size_t ws_size,
                              hipStream_t stream) {
    const float* x          = (const float*)d_in[0];
    const int*   edge_index = (const int*)d_in[1];
    const int*   batch      = (const int*)d_in[2];

    const int N = in_sizes[2];              // 100000
    const int E = in_sizes[1] / 2;          // 1600000
    const int G = out_size / HDIM;          // 2048
    const int B = (N + NPB - 1) / NPB;      // 782 buckets
    const int NBLK = (E + CHUNK - 1) / CHUNK; // 196 chunks (<=256)

    const int* srcs = edge_index;
    const int* dsts = edge_index + E;

    // workspace layout
    char* p = (char*)d_ws;
    float* h      = (float*)p; p += (size_t)N * HDIM * sizeof(float);
    float* xbuf   = (float*)p; p += (size_t)N * HDIM * sizeof(float);
    float* es     = (float*)p; p += (size_t)N * sizeof(float);
    float* ed     = (float*)p; p += (size_t)N * sizeof(float);
    int*   rowptr = (int*)p;   p += (size_t)(N + 1) * sizeof(int);
    int*   csrsrc = (int*)p;   p += (size_t)E * sizeof(int);
    int*   pairs  = (int*)p;   p += (size_t)E * sizeof(int);
    int*   cnt2D  = (int*)p;   p += (size_t)NBLK * B * sizeof(int);
    int*   off2D  = (int*)p;   p += (size_t)NBLK * B * sizeof(int);
    int*   bcnt   = (int*)p;   p += (size_t)B * sizeof(int);
    int*   bstart = (int*)p;   p += (size_t)(B + 1) * sizeof(int);
    float* psum   = (float*)p; p += (size_t)G * HDIM * sizeof(float);
    float* pcnt   = (float*)p; p += (size_t)G * sizeof(float);

    // ---- CSR build (once; same edge set for all 4 layers) ----
    chunk_hist  <<<NBLK, 256, 0, stream>>>(dsts, E, B, cnt2D);
    chunk_scan  <<<B, 256, 0, stream>>>(cnt2D, NBLK, B, off2D, bcnt);
    bucket_scan <<<1, 1024, 0, stream>>>(bcnt, B, E, bstart, rowptr, N);
    pair_scatter2<<<NBLK, 256, 0, stream>>>(srcs, dsts, E, B, off2D, bstart, pairs);
    bucket_sort <<<B, 256, 0, stream>>>(pairs, bstart, rowptr, csrsrc, N);

    // ---- 4 GAT layers ----
    const float* xin = x;
    for (int l = 0; l < 4; l++) {
        const float* W   = (const float*)d_in[3 + 4 * l];
        const float* a_s = (const float*)d_in[4 + 4 * l];
        const float* a_d = (const float*)d_in[5 + 4 * l];
        const float* bb  = (const float*)d_in[6 + 4 * l];

        if (l == 0) gemm128<<<2048, 256, 0, stream>>>(xin, W, a_s, a_d, h, es, ed, N);
        else        gemm32 <<<2048, 256, 0, stream>>>(xin, W, a_s, a_d, h, es, ed, N);

        agg2<<<(N * 8 + 255) / 256, 256, 0, stream>>>(h, es, ed, rowptr, csrsrc, bb, xbuf, N);
        xin = xbuf;
    }

    // ---- global mean pool ----
    hipMemsetAsync(psum, 0, (size_t)(G * HDIM + G) * sizeof(float), stream);
    pool_kernel<<<(N * 32 + 255) / 256, 256, 0, stream>>>(xbuf, batch, psum, pcnt, N);
    pool_div<<<(G * HDIM + 255) / 256, 256, 0, stream>>>(psum, pcnt, (float*)d_out, G);
}

// Round 5
// 451.797 us; speedup vs baseline: 5.6899x; 1.0944x over previous
//
#include <hip/hip_runtime.h>
#include <hip/hip_fp16.h>

#define HDIM 32
#define IN_DIM 128
#define NEG_SLOPE 0.2f
#define NPB 128            // nodes per coarse bucket (power of 2)
#define NPB_SHIFT 7
#define MAXB 1024          // max buckets (B = ceil(N/128) = 782)
#define CHUNK 8192         // edges per chunk block
#define CAP 4096           // max records per bucket for LDS sort fast path

__device__ __forceinline__ float leaky(float e) {
    return (e >= 0.f) ? e : NEG_SLOPE * e;
}

__device__ __forceinline__ float2 h2f(unsigned int u) {
    __half2 h = *reinterpret_cast<__half2*>(&u);
    return __half22float2(h);
}

// ---------------- GEMM kernels (h written as fp16) ----------------

__global__ __launch_bounds__(256) void gemm128(
    const float* __restrict__ x, const float* __restrict__ W,
    const float* __restrict__ a_s, const float* __restrict__ a_d,
    __half* __restrict__ h, float* __restrict__ es, float* __restrict__ ed, int N)
{
    __shared__ float Ws[IN_DIM * HDIM];
    __shared__ float xs[8][IN_DIM];
    const int tid = threadIdx.x;
    for (int i = tid; i < IN_DIM * HDIM; i += 256) Ws[i] = W[i];
    const int col = tid & 31;
    const int rl  = tid >> 5;
    const float as_c = a_s[col], ad_c = a_d[col];
    for (int tile = blockIdx.x; tile * 8 < N; tile += gridDim.x) {
        const int row0 = tile * 8;
        __syncthreads();
        for (int i = tid; i < 8 * IN_DIM; i += 256) {
            int r = i >> 7, c = i & 127;
            int gr = row0 + r;
            xs[r][c] = (gr < N) ? x[(size_t)gr * IN_DIM + c] : 0.f;
        }
        __syncthreads();
        const int row = row0 + rl;
        float acc = 0.f;
        #pragma unroll 8
        for (int k = 0; k < IN_DIM; k++) acc += xs[rl][k] * Ws[k * HDIM + col];
        float ps = acc * as_c, pd = acc * ad_c;
        #pragma unroll
        for (int m = 16; m >= 1; m >>= 1) { ps += __shfl_xor(ps, m); pd += __shfl_xor(pd, m); }
        if (row < N) {
            h[(size_t)row * HDIM + col] = __float2half(acc);
            if (col == 0) { es[row] = ps; ed[row] = pd; }
        }
    }
}

__global__ __launch_bounds__(256) void gemm32(
    const float* __restrict__ x, const float* __restrict__ W,
    const float* __restrict__ a_s, const float* __restrict__ a_d,
    __half* __restrict__ h, float* __restrict__ es, float* __restrict__ ed, int N)
{
    __shared__ float Ws[HDIM * HDIM];
    __shared__ float xs[8][HDIM];
    const int tid = threadIdx.x;
    for (int i = tid; i < HDIM * HDIM; i += 256) Ws[i] = W[i];
    const int col = tid & 31;
    const int rl  = tid >> 5;
    const float as_c = a_s[col], ad_c = a_d[col];
    for (int tile = blockIdx.x; tile * 8 < N; tile += gridDim.x) {
        const int row0 = tile * 8;
        __syncthreads();
        {
            int r = tid >> 5, c = tid & 31;
            int gr = row0 + r;
            xs[r][c] = (gr < N) ? x[(size_t)gr * HDIM + c] : 0.f;
        }
        __syncthreads();
        const int row = row0 + rl;
        float acc = 0.f;
        #pragma unroll
        for (int k = 0; k < HDIM; k++) acc += xs[rl][k] * Ws[k * HDIM + col];
        float ps = acc * as_c, pd = acc * ad_c;
        #pragma unroll
        for (int m = 16; m >= 1; m >>= 1) { ps += __shfl_xor(ps, m); pd += __shfl_xor(pd, m); }
        if (row < N) {
            h[(size_t)row * HDIM + col] = __float2half(acc);
            if (col == 0) { es[row] = ps; ed[row] = pd; }
        }
    }
}

// ---------------- Two-level CSR build (once per call) ----------------

__global__ __launch_bounds__(256) void chunk_hist(
    const int* __restrict__ dsts, int E, int B, int* __restrict__ cnt2D)
{
    __shared__ int hist[MAXB];
    const int blk = blockIdx.x;
    for (int i = threadIdx.x; i < B; i += 256) hist[i] = 0;
    __syncthreads();
    const int e0 = blk * CHUNK;
    for (int i = threadIdx.x; i < CHUNK; i += 256) {
        int e = e0 + i;
        if (e < E) atomicAdd(&hist[dsts[e] >> NPB_SHIFT], 1);
    }
    __syncthreads();
    for (int i = threadIdx.x; i < B; i += 256) cnt2D[(size_t)blk * B + i] = hist[i];
}

__global__ __launch_bounds__(256) void chunk_scan(
    const int* __restrict__ cnt2D, int NBLK, int B,
    int* __restrict__ off2D, int* __restrict__ bcnt)
{
    __shared__ int s[256];
    const int b = blockIdx.x, t = threadIdx.x;
    int v = (t < NBLK) ? cnt2D[(size_t)t * B + b] : 0;
    s[t] = v;
    __syncthreads();
    for (int off = 1; off < 256; off <<= 1) {
        int add = (t >= off) ? s[t - off] : 0;
        __syncthreads();
        s[t] += add;
        __syncthreads();
    }
    if (t < NBLK) off2D[(size_t)t * B + b] = s[t] - v;
    if (t == 255) bcnt[b] = s[255];
}

__global__ __launch_bounds__(1024) void bucket_scan(
    const int* __restrict__ bcnt, int B, int E,
    int* __restrict__ bstart, int* __restrict__ rowptr, int N)
{
    __shared__ int s[1024];
    const int t = threadIdx.x;
    int v = (t < B) ? bcnt[t] : 0;
    s[t] = v;
    __syncthreads();
    for (int off = 1; off < 1024; off <<= 1) {
        int add = (t >= off) ? s[t - off] : 0;
        __syncthreads();
        s[t] += add;
        __syncthreads();
    }
    if (t < B) bstart[t] = s[t] - v;
    if (t == 0) { bstart[B] = E; rowptr[N] = E; }
}

__global__ __launch_bounds__(256) void pair_scatter2(
    const int* __restrict__ srcs, const int* __restrict__ dsts, int E, int B,
    const int* __restrict__ off2D, const int* __restrict__ bstart,
    int* __restrict__ pairs)
{
    __shared__ int cur[MAXB];
    const int blk = blockIdx.x;
    for (int i = threadIdx.x; i < B; i += 256)
        cur[i] = bstart[i] + off2D[(size_t)blk * B + i];
    __syncthreads();
    const int e0 = blk * CHUNK;
    for (int i = threadIdx.x; i < CHUNK; i += 256) {
        int e = e0 + i;
        if (e < E) {
            int s = srcs[e], d = dsts[e];
            int pos = atomicAdd(&cur[d >> NPB_SHIFT], 1);
            pairs[pos] = (s << NPB_SHIFT) | (d & (NPB - 1));
        }
    }
}

__global__ __launch_bounds__(256) void bucket_sort(
    const int* __restrict__ pairs, const int* __restrict__ bstart,
    int* __restrict__ rowptr, int* __restrict__ csrsrc, int N)
{
    __shared__ int ldeg[NPB];
    __shared__ int lex[NPB];
    __shared__ int recs[CAP];
    __shared__ int sorted[CAP];
    const int b = blockIdx.x, t = threadIdx.x;
    const int p0 = bstart[b], p1 = bstart[b + 1];
    const int cnt = p1 - p0;
    if (t < NPB) ldeg[t] = 0;
    __syncthreads();
    for (int i = t; i < cnt; i += 256) {
        int r = pairs[p0 + i];
        atomicAdd(&ldeg[r & (NPB - 1)], 1);
        if (i < CAP) recs[i] = r;
    }
    __syncthreads();
    if (t < NPB) lex[t] = ldeg[t];
    __syncthreads();
    for (int off = 1; off < NPB; off <<= 1) {
        int add = (t >= off && t < NPB) ? lex[t - off] : 0;
        __syncthreads();
        if (t < NPB) lex[t] += add;
        __syncthreads();
    }
    const int node0 = b * NPB;
    if (t < NPB) {
        int excl = lex[t] - ldeg[t];
        if (node0 + t < N) rowptr[node0 + t] = p0 + excl;
        ldeg[t] = excl;
    }
    __syncthreads();
    if (cnt <= CAP) {
        for (int i = t; i < cnt; i += 256) {
            int r = recs[i];
            int pos = atomicAdd(&ldeg[r & (NPB - 1)], 1);
            sorted[pos] = r >> NPB_SHIFT;
        }
        __syncthreads();
        for (int i = t; i < cnt; i += 256) csrsrc[p0 + i] = sorted[i];
    } else {
        for (int i = t; i < cnt; i += 256) {
            int r = pairs[p0 + i];
            int pos = atomicAdd(&ldeg[r & (NPB - 1)], 1);
            csrsrc[p0 + pos] = r >> NPB_SHIFT;
        }
    }
}

// ---------------- Aggregation: 8 lanes/node, fp16 h gather ----------------

__global__ __launch_bounds__(256) void agg2(
    const __half* __restrict__ h, const float* __restrict__ es, const float* __restrict__ ed,
    const int* __restrict__ rowptr, const int* __restrict__ csrsrc,
    const float* __restrict__ b, float* __restrict__ out, int N)
{
    const int gid  = blockIdx.x * 256 + threadIdx.x;
    const int node = gid >> 3;
    const int l    = threadIdx.x & 7;
    if (node >= N) return;

    const int e0 = rowptr[node];
    const int e1 = rowptr[node + 1];
    const float edi = ed[node];
    const uint2* __restrict__ h8 = (const uint2*)h;   // 8 B = 4 halves per lane

    float ax = 0.f, ay = 0.f, az = 0.f, aw = 0.f, den = 0.f;
    #pragma unroll 2
    for (int e = e0; e < e1; e++) {
        int s = csrsrc[e];
        float w = __expf(leaky(es[s] + edi));
        uint2 u = h8[(size_t)s * 8 + l];
        float2 f0 = h2f(u.x), f1 = h2f(u.y);
        ax += w * f0.x; ay += w * f0.y; az += w * f1.x; aw += w * f1.y;
        den += w;
    }
    {   // self-loop
        float w = __expf(leaky(es[node] + edi));
        uint2 u = h8[(size_t)node * 8 + l];
        float2 f0 = h2f(u.x), f1 = h2f(u.y);
        ax += w * f0.x; ay += w * f0.y; az += w * f1.x; aw += w * f1.y;
        den += w;
    }
    float4 bv = ((const float4*)b)[l];
    float inv = 1.f / den;
    float4 o;
    o.x = ax * inv + bv.x; o.y = ay * inv + bv.y;
    o.z = az * inv + bv.z; o.w = aw * inv + bv.w;
    ((float4*)out)[(size_t)node * 8 + l] = o;
}

// ---------------- Pool: run-length accumulation (batch is sorted) ---------

#define PNPG 128   // nodes per 32-lane group

__global__ __launch_bounds__(256) void pool_rle(
    const float* __restrict__ x, const int* __restrict__ batch,
    float* __restrict__ psum, float* __restrict__ pcnt, int N)
{
    const int grp  = (blockIdx.x * 256 + threadIdx.x) >> 5;
    const int lane = threadIdx.x & 31;
    const int n0 = grp * PNPG;
    if (n0 >= N) return;
    const int n1 = (n0 + PNPG < N) ? n0 + PNPG : N;

    int gcur = batch[n0];
    float acc = 0.f, cnt = 0.f;
    for (int i = n0; i < n1; i++) {
        int g = batch[i];
        if (g != gcur) {
            atomicAdd(&psum[(size_t)gcur * HDIM + lane], acc);
            if (lane == 0) atomicAdd(&pcnt[gcur], cnt);
            acc = 0.f; cnt = 0.f; gcur = g;
        }
        acc += x[(size_t)i * HDIM + lane];
        cnt += 1.f;
    }
    atomicAdd(&psum[(size_t)gcur * HDIM + lane], acc);
    if (lane == 0) atomicAdd(&pcnt[gcur], cnt);
}

__global__ __launch_bounds__(256) void pool_div(
    const float* __restrict__ psum, const float* __restrict__ pcnt,
    float* __restrict__ out, int G)
{
    int t = blockIdx.x * blockDim.x + threadIdx.x;
    if (t >= G * HDIM) return;
    int g = t >> 5;
    out[t] = psum[t] / fmaxf(pcnt[g], 1.f);
}

// ---------------- Launch ----------------

extern "C" void kernel_launch(void* const* d_in, const int* in_sizes, int n_in,
                              void* d_out, int out_size, void* d_ws, size_t ws_size,
                              hipStream_t stream) {
    const float* x          = (const float*)d_in[0];
    const int*   edge_index = (const int*)d_in[1];
    const int*   batch      = (const int*)d_in[2];

    const int N = in_sizes[2];              // 100000
    const int E = in_sizes[1] / 2;          // 1600000
    const int G = out_size / HDIM;          // 2048
    const int B = (N + NPB - 1) / NPB;      // 782 buckets
    const int NBLK = (E + CHUNK - 1) / CHUNK;

    const int* srcs = edge_index;
    const int* dsts = edge_index + E;

    // workspace layout
    char* p = (char*)d_ws;
    __half* h     = (__half*)p; p += (size_t)N * HDIM * sizeof(__half);
    float* xbuf   = (float*)p; p += (size_t)N * HDIM * sizeof(float);
    float* es     = (float*)p; p += (size_t)N * sizeof(float);
    float* ed     = (float*)p; p += (size_t)N * sizeof(float);
    int*   rowptr = (int*)p;   p += (size_t)(N + 1) * sizeof(int);
    int*   csrsrc = (int*)p;   p += (size_t)E * sizeof(int);
    int*   pairs  = (int*)p;   p += (size_t)E * sizeof(int);
    int*   cnt2D  = (int*)p;   p += (size_t)NBLK * B * sizeof(int);
    int*   off2D  = (int*)p;   p += (size_t)NBLK * B * sizeof(int);
    int*   bcnt   = (int*)p;   p += (size_t)B * sizeof(int);
    int*   bstart = (int*)p;   p += (size_t)(B + 1) * sizeof(int);
    float* psum   = (float*)p; p += (size_t)G * HDIM * sizeof(float);
    float* pcnt   = (float*)p; p += (size_t)G * sizeof(float);

    // ---- CSR build (once; same edge set for all 4 layers) ----
    chunk_hist  <<<NBLK, 256, 0, stream>>>(dsts, E, B, cnt2D);
    chunk_scan  <<<B, 256, 0, stream>>>(cnt2D, NBLK, B, off2D, bcnt);
    bucket_scan <<<1, 1024, 0, stream>>>(bcnt, B, E, bstart, rowptr, N);
    pair_scatter2<<<NBLK, 256, 0, stream>>>(srcs, dsts, E, B, off2D, bstart, pairs);
    bucket_sort <<<B, 256, 0, stream>>>(pairs, bstart, rowptr, csrsrc, N);

    // ---- 4 GAT layers ----
    const float* xin = x;
    for (int l = 0; l < 4; l++) {
        const float* W   = (const float*)d_in[3 + 4 * l];
        const float* a_s = (const float*)d_in[4 + 4 * l];
        const float* a_d = (const float*)d_in[5 + 4 * l];
        const float* bb  = (const float*)d_in[6 + 4 * l];

        if (l == 0) gemm128<<<2048, 256, 0, stream>>>(xin, W, a_s, a_d, h, es, ed, N);
        else        gemm32 <<<2048, 256, 0, stream>>>(xin, W, a_s, a_d, h, es, ed, N);

        agg2<<<(N * 8 + 255) / 256, 256, 0, stream>>>(h, es, ed, rowptr, csrsrc, bb, xbuf, N);
        xin = xbuf;
    }

    // ---- global mean pool ----
    hipMemsetAsync(psum, 0, (size_t)(G * HDIM + G) * sizeof(float), stream);
    pool_rle<<<((N + PNPG - 1) / PNPG * 32 + 255) / 256, 256, 0, stream>>>(xbuf, batch, psum, pcnt, N);
    pool_div<<<(G * HDIM + 255) / 256, 256, 0, stream>>>(psum, pcnt, (float*)d_out, G);
}